// Round 2
// baseline (296.804 us; speedup 1.0000x reference)
//
#include <hip/hip_runtime.h>

#define DIM   256
#define DH    64
#define NKS   64      // K_SLOTS
#define NH    4       // HEADS
#define SEQ   32768

typedef float f32x4  __attribute__((ext_vector_type(4)));
typedef short bf16x8 __attribute__((ext_vector_type(8)));

__device__ __forceinline__ unsigned short f2bf(float f) {
    union { float f; unsigned int u; } v; v.f = f;
    return (unsigned short)((v.u + 0x7FFFu + ((v.u >> 16) & 1u)) >> 16);  // RNE
}

// ---------------- K0: Q = LN(mu) @ Wq + bq  -> Q[64][256] fp32 ----------------
__global__ void k_q(const float* __restrict__ mu, const float* __restrict__ g,
                    const float* __restrict__ bb, const float* __restrict__ Wq,
                    const float* __restrict__ bq, float* __restrict__ Q) {
    __shared__ float nrm[DIM];
    __shared__ float red1[4], red2[4];
    const int k = blockIdx.x, t = threadIdx.x;
    float x = mu[k * DIM + t];
    float s = x;
    #pragma unroll
    for (int o = 1; o <= 32; o <<= 1) s += __shfl_xor(s, o);
    if ((t & 63) == 0) red1[t >> 6] = s;
    __syncthreads();
    const float mean = (red1[0] + red1[1] + red1[2] + red1[3]) * (1.0f / DIM);
    const float d = x - mean;
    float vs = d * d;
    #pragma unroll
    for (int o = 1; o <= 32; o <<= 1) vs += __shfl_xor(vs, o);
    if ((t & 63) == 0) red2[t >> 6] = vs;
    __syncthreads();
    const float var = (red2[0] + red2[1] + red2[2] + red2[3]) * (1.0f / DIM);
    nrm[t] = d * rsqrtf(var + 1e-5f) * g[t] + bb[t];
    __syncthreads();
    float acc = bq[t];
    for (int c = 0; c < DIM; ++c) acc += nrm[c] * Wq[c * DIM + t];
    Q[k * DIM + t] = acc;
}

// ---- K1: fold scores matrix + transpose. W2T[n][c] (bf16, c contiguous) ----
__global__ void k_fold(const float* __restrict__ Q, const float* __restrict__ Wk,
                       const float* __restrict__ bk, const float* __restrict__ Wv,
                       const float* __restrict__ bv,
                       unsigned short* __restrict__ W2T, float* __restrict__ b2) {
    const int n = blockIdx.x, t = threadIdx.x;
    __shared__ float q[DH];
    if (n < 256) {
        const int h = n >> 6, k = n & 63;
        if (t < DH) q[t] = Q[k * DIM + h * DH + t];
        __syncthreads();
        float acc = 0.f;
        #pragma unroll 8
        for (int d0 = 0; d0 < DH; ++d0) acc += Wk[t * DIM + h * DH + d0] * q[d0];
        W2T[n * 256 + t] = f2bf(acc * 0.125f);
        if (t == 0) {
            float ba = 0.f;
            for (int d0 = 0; d0 < DH; ++d0) ba += bk[h * DH + d0] * q[d0];
            b2[n] = ba * 0.125f;
        }
    } else {
        const int col = n - 256;
        W2T[n * 256 + t] = f2bf(Wv[t * DIM + col]);
        if (t == 0) b2[n] = bv[col];
    }
}

// ---------------- K2: fused main kernel, pipelined ----------------
// 512 blocks (b = bid>>7, chunk = bid&127 -> 256 rows = 8 tiles of 32), 8 waves.
// LDS: Xbuf0 @0 (16K), Xbuf1 @16384 (16K), A @32768 (16K: [4h][64k][32s]),
//      V @49152 (16K: [256d][32s]). Per tile (2 barriers):
//   [A] issue next-tile X loads (regs, in flight across compute)
//   [B] Y[32x512] = X@W2 (MFMA from Xbuf[cur] + L2-resident W2T)
//   [C] softmax (waves 0-3) / V pack (waves 4-7) into registers
//   [D] barrier  (P4(t-1) A/V reads done; Xbuf[cur] reads done)
//   [E] write A/V; cvt+write Xbuf[cur^1]
//   [F] barrier  (A/V + next X visible)
//   [G] PV MFMA, persistent fp32 accum
__global__ __launch_bounds__(512, 4)
void k_main(const float* __restrict__ X, const unsigned short* __restrict__ W2T,
            const float* __restrict__ b2, float* __restrict__ num,
            float* __restrict__ den) {
    __shared__ __align__(16) unsigned char smem[65536];
    const int tid  = threadIdx.x;
    const int lane = tid & 63;
    const int wid  = tid >> 6;
    const int l15  = lane & 15;
    const int lhi  = lane >> 4;
    const int b     = blockIdx.x >> 7;
    const int chunk = blockIdx.x & 127;
    const float* Xg = X + ((size_t)(b * SEQ + chunk * 256)) * DIM;

    const int hp = wid >> 1;
    const int dhalf = (wid & 1) * 32;

    f32x4 pv[4][2];
    #pragma unroll
    for (int i = 0; i < 4; ++i)
        #pragma unroll
        for (int j = 0; j < 2; ++j) pv[i][j] = (f32x4){0.f, 0.f, 0.f, 0.f};
    float den_acc[4] = {0.f, 0.f, 0.f, 0.f};

    float bias[4];
    #pragma unroll
    for (int ni = 0; ni < 4; ++ni) bias[ni] = b2[wid * 64 + ni * 16 + l15];

    float4 pf[4];
    // ---- prologue: stage tile 0 ----
    #pragma unroll
    for (int j = 0; j < 4; ++j) {
        const int f = j * 512 + tid;
        pf[j] = *(const float4*)(Xg + (f >> 6) * DIM + (f & 63) * 4);
    }
    #pragma unroll
    for (int j = 0; j < 4; ++j) {
        const int f = j * 512 + tid;
        const int row = f >> 6, c4 = f & 63;
        const unsigned int lo = (unsigned int)f2bf(pf[j].x) | ((unsigned int)f2bf(pf[j].y) << 16);
        const unsigned int hi = (unsigned int)f2bf(pf[j].z) | ((unsigned int)f2bf(pf[j].w) << 16);
        const int byte = row * 512 + ((c4 * 8) ^ ((row & 7) << 4));
        *(uint2*)(smem + byte) = make_uint2(lo, hi);
    }
    __syncthreads();

    for (int t = 0; t < 8; ++t) {
        const int cur = t & 1;
        const unsigned char* xbuf = smem + cur * 16384;

        // ---- [A] issue next-tile loads ----
        if (t < 7) {
            const float* Xt = Xg + (size_t)(t + 1) * 32 * DIM;
            #pragma unroll
            for (int j = 0; j < 4; ++j) {
                const int f = j * 512 + tid;
                pf[j] = *(const float4*)(Xt + (f >> 6) * DIM + (f & 63) * 4);
            }
        }

        // ---- [B] Y-GEMM: rows 0..31, wave cols [wid*64, wid*64+64) ----
        f32x4 acc[2][4];
        #pragma unroll
        for (int si = 0; si < 2; ++si)
            #pragma unroll
            for (int ni = 0; ni < 4; ++ni) acc[si][ni] = (f32x4){0.f, 0.f, 0.f, 0.f};

        #pragma unroll
        for (int ks = 0; ks < 8; ++ks) {
            bf16x8 afr[2];
            #pragma unroll
            for (int si = 0; si < 2; ++si) {
                const int row  = si * 16 + l15;
                const int byte = row * 512 + ((ks * 64 + lhi * 16) ^ ((row & 7) << 4));
                afr[si] = *(const bf16x8*)(xbuf + byte);
            }
            #pragma unroll
            for (int ni = 0; ni < 4; ++ni) {
                const unsigned short* bp =
                    W2T + (size_t)(wid * 64 + ni * 16 + l15) * 256 + ks * 32 + lhi * 8;
                const bf16x8 bfr = *(const bf16x8*)bp;
                #pragma unroll
                for (int si = 0; si < 2; ++si)
                    acc[si][ni] = __builtin_amdgcn_mfma_f32_16x16x32_bf16(
                        afr[si], bfr, acc[si][ni], 0, 0, 0);
            }
        }

        // ---- [C] softmax / V pack into registers ----
        uint2 pk[2][4];
        if (wid < 4) {
            #pragma unroll
            for (int si = 0; si < 2; ++si) {
                float x[4][4];
                #pragma unroll
                for (int ni = 0; ni < 4; ++ni)
                    #pragma unroll
                    for (int r = 0; r < 4; ++r) x[ni][r] = acc[si][ni][r] + bias[ni];
                float m[4];
                #pragma unroll
                for (int r = 0; r < 4; ++r) {
                    m[r] = fmaxf(fmaxf(x[0][r], x[1][r]), fmaxf(x[2][r], x[3][r]));
                    m[r] = fmaxf(m[r], __shfl_xor(m[r], 1));
                    m[r] = fmaxf(m[r], __shfl_xor(m[r], 2));
                    m[r] = fmaxf(m[r], __shfl_xor(m[r], 4));
                    m[r] = fmaxf(m[r], __shfl_xor(m[r], 8));
                }
                float sm[4] = {0.f, 0.f, 0.f, 0.f};
                #pragma unroll
                for (int ni = 0; ni < 4; ++ni)
                    #pragma unroll
                    for (int r = 0; r < 4; ++r) {
                        x[ni][r] = __expf(x[ni][r] - m[r]);
                        sm[r] += x[ni][r];
                    }
                #pragma unroll
                for (int r = 0; r < 4; ++r) {
                    sm[r] += __shfl_xor(sm[r], 1);
                    sm[r] += __shfl_xor(sm[r], 2);
                    sm[r] += __shfl_xor(sm[r], 4);
                    sm[r] += __shfl_xor(sm[r], 8);
                    sm[r] = 1.0f / sm[r];
                }
                #pragma unroll
                for (int ni = 0; ni < 4; ++ni) {
                    const float w0 = x[ni][0] * sm[0], w1 = x[ni][1] * sm[1];
                    const float w2 = x[ni][2] * sm[2], w3 = x[ni][3] * sm[3];
                    den_acc[ni] += (w0 + w1) + (w2 + w3);
                    pk[si][ni] = make_uint2(
                        (unsigned int)f2bf(w0) | ((unsigned int)f2bf(w1) << 16),
                        (unsigned int)f2bf(w2) | ((unsigned int)f2bf(w3) << 16));
                }
            }
        } else {
            #pragma unroll
            for (int si = 0; si < 2; ++si)
                #pragma unroll
                for (int ni = 0; ni < 4; ++ni) {
                    const float v0 = acc[si][ni][0] + bias[ni];
                    const float v1 = acc[si][ni][1] + bias[ni];
                    const float v2 = acc[si][ni][2] + bias[ni];
                    const float v3 = acc[si][ni][3] + bias[ni];
                    pk[si][ni] = make_uint2(
                        (unsigned int)f2bf(v0) | ((unsigned int)f2bf(v1) << 16),
                        (unsigned int)f2bf(v2) | ((unsigned int)f2bf(v3) << 16));
                }
        }

        // ---- [D] barrier ----
        __syncthreads();

        // ---- [E] write A/V ; write next X buf ----
        if (wid < 4) {
            #pragma unroll
            for (int si = 0; si < 2; ++si)
                #pragma unroll
                for (int ni = 0; ni < 4; ++ni) {
                    const int k    = ni * 16 + l15;
                    const int sb   = si * 32 + lhi * 8;
                    const int byte = 32768 + wid * 4096 + k * 64 + (sb ^ ((k & 3) << 4));
                    *(uint2*)(smem + byte) = pk[si][ni];
                }
        } else {
            #pragma unroll
            for (int si = 0; si < 2; ++si)
                #pragma unroll
                for (int ni = 0; ni < 4; ++ni) {
                    const int d    = (wid - 4) * 64 + ni * 16 + l15;
                    const int sb   = si * 32 + lhi * 8;
                    const int byte = 49152 + d * 64 + (sb ^ ((d & 3) << 4));
                    *(uint2*)(smem + byte) = pk[si][ni];
                }
        }
        if (t < 7) {
            unsigned char* nbuf = smem + (cur ^ 1) * 16384;
            #pragma unroll
            for (int j = 0; j < 4; ++j) {
                const int f = j * 512 + tid;
                const int row = f >> 6, c4 = f & 63;
                const unsigned int lo = (unsigned int)f2bf(pf[j].x) | ((unsigned int)f2bf(pf[j].y) << 16);
                const unsigned int hi = (unsigned int)f2bf(pf[j].z) | ((unsigned int)f2bf(pf[j].w) << 16);
                const int byte = row * 512 + ((c4 * 8) ^ ((row & 7) << 4));
                *(uint2*)(nbuf + byte) = make_uint2(lo, hi);
            }
        }

        // ---- [F] barrier ----
        __syncthreads();

        // ---- [G] PV: num_h[k][d] += A_h[k,s] * V[s, h*64+d]  (K=32, 1 step) ----
        bf16x8 afr[4];
        #pragma unroll
        for (int mi = 0; mi < 4; ++mi) {
            const int k    = mi * 16 + l15;
            const int byte = 32768 + hp * 4096 + k * 64 + ((lhi * 16) ^ ((k & 3) << 4));
            afr[mi] = *(const bf16x8*)(smem + byte);
        }
        bf16x8 bfr[2];
        #pragma unroll
        for (int ni = 0; ni < 2; ++ni) {
            const int d    = hp * 64 + dhalf + ni * 16 + l15;
            const int byte = 49152 + d * 64 + ((lhi * 16) ^ ((d & 3) << 4));
            bfr[ni] = *(const bf16x8*)(smem + byte);
        }
        #pragma unroll
        for (int mi = 0; mi < 4; ++mi)
            #pragma unroll
            for (int ni = 0; ni < 2; ++ni)
                pv[mi][ni] = __builtin_amdgcn_mfma_f32_16x16x32_bf16(
                    afr[mi], bfr[ni], pv[mi][ni], 0, 0, 0);
    }

    // ---- epilogue: global partial accumulation ----
    if (wid < 4) {
        #pragma unroll
        for (int ni = 0; ni < 4; ++ni) {
            float v = den_acc[ni];
            v += __shfl_xor(v, 16);
            v += __shfl_xor(v, 32);
            if (lhi == 0)
                atomicAdd(&den[(b * NH + wid) * NKS + ni * 16 + l15], v);
        }
    }
    #pragma unroll
    for (int mi = 0; mi < 4; ++mi)
        #pragma unroll
        for (int ni = 0; ni < 2; ++ni)
            #pragma unroll
            for (int r = 0; r < 4; ++r) {
                const int k = mi * 16 + lhi * 4 + r;
                const int d = dhalf + ni * 16 + l15;
                atomicAdd(&num[((size_t)((b * NH + hp) * NKS) + k) * DH + d], pv[mi][ni][r]);
            }
}

// ---------------- K3: S_hat = num/(den+eps); out = LN(S_hat) ----------------
__global__ void k_final(const float* __restrict__ num, const float* __restrict__ den,
                        const float* __restrict__ ga, const float* __restrict__ gb,
                        float* __restrict__ out) {
    __shared__ float red1[4], red2[4];
    const int b = blockIdx.x >> 6, k = blockIdx.x & 63;
    const int t = threadIdx.x;
    const int h = t >> 6, dd = t & 63;
    const float dn  = den[(b * NH + h) * NKS + k] + 1e-20f;
    const float val = num[((size_t)((b * NH + h) * NKS) + k) * DH + dd] / dn;
    float s = val;
    #pragma unroll
    for (int o = 1; o <= 32; o <<= 1) s += __shfl_xor(s, o);
    if ((t & 63) == 0) red1[t >> 6] = s;
    __syncthreads();
    const float mean = (red1[0] + red1[1] + red1[2] + red1[3]) * (1.0f / DIM);
    const float d = val - mean;
    float vs = d * d;
    #pragma unroll
    for (int o = 1; o <= 32; o <<= 1) vs += __shfl_xor(vs, o);
    if ((t & 63) == 0) red2[t >> 6] = vs;
    __syncthreads();
    const float var = (red2[0] + red2[1] + red2[2] + red2[3]) * (1.0f / DIM);
    out[(size_t)(b * NKS + k) * DIM + t] = d * rsqrtf(var + 1e-5f) * ga[t] + gb[t];
}

extern "C" void kernel_launch(void* const* d_in, const int* in_sizes, int n_in,
                              void* d_out, int out_size, void* d_ws, size_t ws_size,
                              hipStream_t stream) {
    const float* X      = (const float*)d_in[0];
    const float* mu     = (const float*)d_in[1];
    const float* ln_s_g = (const float*)d_in[2];
    const float* ln_s_b = (const float*)d_in[3];
    const float* Wq     = (const float*)d_in[4];
    const float* bq     = (const float*)d_in[5];
    const float* Wk     = (const float*)d_in[6];
    const float* bk     = (const float*)d_in[7];
    const float* Wv     = (const float*)d_in[8];
    const float* bv     = (const float*)d_in[9];
    const float* ln_a_g = (const float*)d_in[10];
    const float* ln_a_b = (const float*)d_in[11];
    float* out = (float*)d_out;

    char* ws = (char*)d_ws;
    float*          Q   = (float*)(ws);                  //  65536 B
    unsigned short* W2T = (unsigned short*)(ws + 65536); // 262144 B
    float*          b2  = (float*)(ws + 327680);         //   2048 B
    float*          num = (float*)(ws + 329728);         // 262144 B
    float*          den = (float*)(ws + 591872);         //   4096 B

    hipMemsetAsync(ws + 329728, 0, 262144 + 4096, stream);  // zero num+den
    hipLaunchKernelGGL(k_q,     dim3(64),  dim3(256), 0, stream, mu, ln_s_g, ln_s_b, Wq, bq, Q);
    hipLaunchKernelGGL(k_fold,  dim3(512), dim3(256), 0, stream, Q, Wk, bk, Wv, bv, W2T, b2);
    hipLaunchKernelGGL(k_main,  dim3(512), dim3(512), 0, stream, X, W2T, b2, num, den);
    hipLaunchKernelGGL(k_final, dim3(256), dim3(256), 0, stream, num, den, ln_a_g, ln_a_b, out);
}

// Round 3
// 167.672 us; speedup vs baseline: 1.7701x; 1.7701x over previous
//
#include <hip/hip_runtime.h>

#define DIM   256
#define DH    64
#define NKS   64      // K_SLOTS
#define NH    4       // HEADS
#define SEQ   32768

typedef float f32x4  __attribute__((ext_vector_type(4)));
typedef short bf16x8 __attribute__((ext_vector_type(8)));

__device__ __forceinline__ unsigned short f2bf(float f) {
    union { float f; unsigned int u; } v; v.f = f;
    return (unsigned short)((v.u + 0x7FFFu + ((v.u >> 16) & 1u)) >> 16);  // RNE
}

// ---------------- K0: Q = LN(mu) @ Wq + bq  -> Q[64][256] fp32 ----------------
__global__ void k_q(const float* __restrict__ mu, const float* __restrict__ g,
                    const float* __restrict__ bb, const float* __restrict__ Wq,
                    const float* __restrict__ bq, float* __restrict__ Q) {
    __shared__ float nrm[DIM];
    __shared__ float red1[4], red2[4];
    const int k = blockIdx.x, t = threadIdx.x;
    float x = mu[k * DIM + t];
    float s = x;
    #pragma unroll
    for (int o = 1; o <= 32; o <<= 1) s += __shfl_xor(s, o);
    if ((t & 63) == 0) red1[t >> 6] = s;
    __syncthreads();
    const float mean = (red1[0] + red1[1] + red1[2] + red1[3]) * (1.0f / DIM);
    const float d = x - mean;
    float vs = d * d;
    #pragma unroll
    for (int o = 1; o <= 32; o <<= 1) vs += __shfl_xor(vs, o);
    if ((t & 63) == 0) red2[t >> 6] = vs;
    __syncthreads();
    const float var = (red2[0] + red2[1] + red2[2] + red2[3]) * (1.0f / DIM);
    nrm[t] = d * rsqrtf(var + 1e-5f) * g[t] + bb[t];
    __syncthreads();
    float acc = bq[t];
    for (int c = 0; c < DIM; ++c) acc += nrm[c] * Wq[c * DIM + t];
    Q[k * DIM + t] = acc;
}

// ---- K1: fold scores matrix + transpose. W2T[n][c] (bf16, c contiguous) ----
__global__ void k_fold(const float* __restrict__ Q, const float* __restrict__ Wk,
                       const float* __restrict__ bk, const float* __restrict__ Wv,
                       const float* __restrict__ bv,
                       unsigned short* __restrict__ W2T, float* __restrict__ b2) {
    const int n = blockIdx.x, t = threadIdx.x;
    __shared__ float q[DH];
    if (n < 256) {
        const int h = n >> 6, k = n & 63;
        if (t < DH) q[t] = Q[k * DIM + h * DH + t];
        __syncthreads();
        float acc = 0.f;
        #pragma unroll 8
        for (int d0 = 0; d0 < DH; ++d0) acc += Wk[t * DIM + h * DH + d0] * q[d0];
        W2T[n * 256 + t] = f2bf(acc * 0.125f);
        if (t == 0) {
            float ba = 0.f;
            for (int d0 = 0; d0 < DH; ++d0) ba += bk[h * DH + d0] * q[d0];
            b2[n] = ba * 0.125f;
        }
    } else {
        const int col = n - 256;
        W2T[n * 256 + t] = f2bf(Wv[t * DIM + col]);
        if (t == 0) b2[n] = bv[col];
    }
}

// ---------------- K2: fused main kernel, pipelined ----------------
// 512 blocks (b = bid>>7, chunk = bid&127 -> 256 rows = 8 tiles of 32), 8 waves.
// LDS: Xbuf0 @0 (16K), Xbuf1 @16384 (16K), A @32768 (16K: [4h][64k][32s]),
//      V @49152 (16K: [256d][32s]). Per tile (2 barriers):
//   [A] issue next-tile X loads (regs, in flight across compute)
//   [B] Y[32x512] = X@W2 (MFMA from Xbuf[cur] + L2-resident W2T)
//   [C] softmax (waves 0-3) / V pack (waves 4-7) into registers
//   [D] barrier  (PV(t-1) A/V reads done; Xbuf[cur] reads done)
//   [E] write A/V; cvt+write Xbuf[cur^1]
//   [F] barrier  (A/V + next X visible)
//   [G] PV MFMA, persistent fp32 accum
// NOTE: __launch_bounds__ min-waves arg MUST stay 2. Setting 4 caps arch-VGPR
// at 64 -> pipeline state spills to scratch (round-2 post-mortem: FETCH 720MB,
// WRITE 300MB, 291us). 128 VGPR / zero spill is the working point.
__global__ __launch_bounds__(512, 2)
void k_main(const float* __restrict__ X, const unsigned short* __restrict__ W2T,
            const float* __restrict__ b2, float* __restrict__ num,
            float* __restrict__ den) {
    __shared__ __align__(16) unsigned char smem[65536];
    const int tid  = threadIdx.x;
    const int lane = tid & 63;
    const int wid  = tid >> 6;
    const int l15  = lane & 15;
    const int lhi  = lane >> 4;
    const int b     = blockIdx.x >> 7;
    const int chunk = blockIdx.x & 127;
    const float* Xg = X + ((size_t)(b * SEQ + chunk * 256)) * DIM;

    const int hp = wid >> 1;
    const int dhalf = (wid & 1) * 32;

    f32x4 pv[4][2];
    #pragma unroll
    for (int i = 0; i < 4; ++i)
        #pragma unroll
        for (int j = 0; j < 2; ++j) pv[i][j] = (f32x4){0.f, 0.f, 0.f, 0.f};
    float den_acc[4] = {0.f, 0.f, 0.f, 0.f};

    float bias[4];
    #pragma unroll
    for (int ni = 0; ni < 4; ++ni) bias[ni] = b2[wid * 64 + ni * 16 + l15];

    float4 pf[4];
    // ---- prologue: stage tile 0 ----
    #pragma unroll
    for (int j = 0; j < 4; ++j) {
        const int f = j * 512 + tid;
        pf[j] = *(const float4*)(Xg + (f >> 6) * DIM + (f & 63) * 4);
    }
    #pragma unroll
    for (int j = 0; j < 4; ++j) {
        const int f = j * 512 + tid;
        const int row = f >> 6, c4 = f & 63;
        const unsigned int lo = (unsigned int)f2bf(pf[j].x) | ((unsigned int)f2bf(pf[j].y) << 16);
        const unsigned int hi = (unsigned int)f2bf(pf[j].z) | ((unsigned int)f2bf(pf[j].w) << 16);
        const int byte = row * 512 + ((c4 * 8) ^ ((row & 7) << 4));
        *(uint2*)(smem + byte) = make_uint2(lo, hi);
    }
    __syncthreads();

    for (int t = 0; t < 8; ++t) {
        const int cur = t & 1;
        const unsigned char* xbuf = smem + cur * 16384;

        // ---- [A] issue next-tile loads ----
        if (t < 7) {
            const float* Xt = Xg + (size_t)(t + 1) * 32 * DIM;
            #pragma unroll
            for (int j = 0; j < 4; ++j) {
                const int f = j * 512 + tid;
                pf[j] = *(const float4*)(Xt + (f >> 6) * DIM + (f & 63) * 4);
            }
        }

        // ---- [B] Y-GEMM: rows 0..31, wave cols [wid*64, wid*64+64) ----
        f32x4 acc[2][4];
        #pragma unroll
        for (int si = 0; si < 2; ++si)
            #pragma unroll
            for (int ni = 0; ni < 4; ++ni) acc[si][ni] = (f32x4){0.f, 0.f, 0.f, 0.f};

        #pragma unroll
        for (int ks = 0; ks < 8; ++ks) {
            bf16x8 afr[2];
            #pragma unroll
            for (int si = 0; si < 2; ++si) {
                const int row  = si * 16 + l15;
                const int byte = row * 512 + ((ks * 64 + lhi * 16) ^ ((row & 7) << 4));
                afr[si] = *(const bf16x8*)(xbuf + byte);
            }
            #pragma unroll
            for (int ni = 0; ni < 4; ++ni) {
                const unsigned short* bp =
                    W2T + (size_t)(wid * 64 + ni * 16 + l15) * 256 + ks * 32 + lhi * 8;
                const bf16x8 bfr = *(const bf16x8*)bp;
                #pragma unroll
                for (int si = 0; si < 2; ++si)
                    acc[si][ni] = __builtin_amdgcn_mfma_f32_16x16x32_bf16(
                        afr[si], bfr, acc[si][ni], 0, 0, 0);
            }
        }

        // ---- [C] softmax / V pack into registers ----
        uint2 pk[2][4];
        if (wid < 4) {
            #pragma unroll
            for (int si = 0; si < 2; ++si) {
                float x[4][4];
                #pragma unroll
                for (int ni = 0; ni < 4; ++ni)
                    #pragma unroll
                    for (int r = 0; r < 4; ++r) x[ni][r] = acc[si][ni][r] + bias[ni];
                float m[4];
                #pragma unroll
                for (int r = 0; r < 4; ++r) {
                    m[r] = fmaxf(fmaxf(x[0][r], x[1][r]), fmaxf(x[2][r], x[3][r]));
                    m[r] = fmaxf(m[r], __shfl_xor(m[r], 1));
                    m[r] = fmaxf(m[r], __shfl_xor(m[r], 2));
                    m[r] = fmaxf(m[r], __shfl_xor(m[r], 4));
                    m[r] = fmaxf(m[r], __shfl_xor(m[r], 8));
                }
                float sm[4] = {0.f, 0.f, 0.f, 0.f};
                #pragma unroll
                for (int ni = 0; ni < 4; ++ni)
                    #pragma unroll
                    for (int r = 0; r < 4; ++r) {
                        x[ni][r] = __expf(x[ni][r] - m[r]);
                        sm[r] += x[ni][r];
                    }
                #pragma unroll
                for (int r = 0; r < 4; ++r) {
                    sm[r] += __shfl_xor(sm[r], 1);
                    sm[r] += __shfl_xor(sm[r], 2);
                    sm[r] += __shfl_xor(sm[r], 4);
                    sm[r] += __shfl_xor(sm[r], 8);
                    sm[r] = 1.0f / sm[r];
                }
                #pragma unroll
                for (int ni = 0; ni < 4; ++ni) {
                    const float w0 = x[ni][0] * sm[0], w1 = x[ni][1] * sm[1];
                    const float w2 = x[ni][2] * sm[2], w3 = x[ni][3] * sm[3];
                    den_acc[ni] += (w0 + w1) + (w2 + w3);
                    pk[si][ni] = make_uint2(
                        (unsigned int)f2bf(w0) | ((unsigned int)f2bf(w1) << 16),
                        (unsigned int)f2bf(w2) | ((unsigned int)f2bf(w3) << 16));
                }
            }
        } else {
            #pragma unroll
            for (int si = 0; si < 2; ++si)
                #pragma unroll
                for (int ni = 0; ni < 4; ++ni) {
                    const float v0 = acc[si][ni][0] + bias[ni];
                    const float v1 = acc[si][ni][1] + bias[ni];
                    const float v2 = acc[si][ni][2] + bias[ni];
                    const float v3 = acc[si][ni][3] + bias[ni];
                    pk[si][ni] = make_uint2(
                        (unsigned int)f2bf(v0) | ((unsigned int)f2bf(v1) << 16),
                        (unsigned int)f2bf(v2) | ((unsigned int)f2bf(v3) << 16));
                }
        }

        // ---- [D] barrier ----
        __syncthreads();

        // ---- [E] write A/V ; write next X buf ----
        if (wid < 4) {
            #pragma unroll
            for (int si = 0; si < 2; ++si)
                #pragma unroll
                for (int ni = 0; ni < 4; ++ni) {
                    const int k    = ni * 16 + l15;
                    const int sb   = si * 32 + lhi * 8;
                    const int byte = 32768 + wid * 4096 + k * 64 + (sb ^ ((k & 3) << 4));
                    *(uint2*)(smem + byte) = pk[si][ni];
                }
        } else {
            #pragma unroll
            for (int si = 0; si < 2; ++si)
                #pragma unroll
                for (int ni = 0; ni < 4; ++ni) {
                    const int d    = (wid - 4) * 64 + ni * 16 + l15;
                    const int sb   = si * 32 + lhi * 8;
                    const int byte = 49152 + d * 64 + (sb ^ ((d & 3) << 4));
                    *(uint2*)(smem + byte) = pk[si][ni];
                }
        }
        if (t < 7) {
            unsigned char* nbuf = smem + (cur ^ 1) * 16384;
            #pragma unroll
            for (int j = 0; j < 4; ++j) {
                const int f = j * 512 + tid;
                const int row = f >> 6, c4 = f & 63;
                const unsigned int lo = (unsigned int)f2bf(pf[j].x) | ((unsigned int)f2bf(pf[j].y) << 16);
                const unsigned int hi = (unsigned int)f2bf(pf[j].z) | ((unsigned int)f2bf(pf[j].w) << 16);
                const int byte = row * 512 + ((c4 * 8) ^ ((row & 7) << 4));
                *(uint2*)(nbuf + byte) = make_uint2(lo, hi);
            }
        }

        // ---- [F] barrier ----
        __syncthreads();

        // ---- [G] PV: num_h[k][d] += A_h[k,s] * V[s, h*64+d]  (K=32, 1 step) ----
        bf16x8 afr[4];
        #pragma unroll
        for (int mi = 0; mi < 4; ++mi) {
            const int k    = mi * 16 + l15;
            const int byte = 32768 + hp * 4096 + k * 64 + ((lhi * 16) ^ ((k & 3) << 4));
            afr[mi] = *(const bf16x8*)(smem + byte);
        }
        bf16x8 bfr[2];
        #pragma unroll
        for (int ni = 0; ni < 2; ++ni) {
            const int d    = hp * 64 + dhalf + ni * 16 + l15;
            const int byte = 49152 + d * 64 + ((lhi * 16) ^ ((d & 3) << 4));
            bfr[ni] = *(const bf16x8*)(smem + byte);
        }
        #pragma unroll
        for (int mi = 0; mi < 4; ++mi)
            #pragma unroll
            for (int ni = 0; ni < 2; ++ni)
                pv[mi][ni] = __builtin_amdgcn_mfma_f32_16x16x32_bf16(
                    afr[mi], bfr[ni], pv[mi][ni], 0, 0, 0);
    }

    // ---- epilogue: global partial accumulation ----
    if (wid < 4) {
        #pragma unroll
        for (int ni = 0; ni < 4; ++ni) {
            float v = den_acc[ni];
            v += __shfl_xor(v, 16);
            v += __shfl_xor(v, 32);
            if (lhi == 0)
                atomicAdd(&den[(b * NH + wid) * NKS + ni * 16 + l15], v);
        }
    }
    #pragma unroll
    for (int mi = 0; mi < 4; ++mi)
        #pragma unroll
        for (int ni = 0; ni < 2; ++ni)
            #pragma unroll
            for (int r = 0; r < 4; ++r) {
                const int k = mi * 16 + lhi * 4 + r;
                const int d = dhalf + ni * 16 + l15;
                atomicAdd(&num[((size_t)((b * NH + hp) * NKS) + k) * DH + d], pv[mi][ni][r]);
            }
}

// ---------------- K3: S_hat = num/(den+eps); out = LN(S_hat) ----------------
__global__ void k_final(const float* __restrict__ num, const float* __restrict__ den,
                        const float* __restrict__ ga, const float* __restrict__ gb,
                        float* __restrict__ out) {
    __shared__ float red1[4], red2[4];
    const int b = blockIdx.x >> 6, k = blockIdx.x & 63;
    const int t = threadIdx.x;
    const int h = t >> 6, dd = t & 63;
    const float dn  = den[(b * NH + h) * NKS + k] + 1e-20f;
    const float val = num[((size_t)((b * NH + h) * NKS) + k) * DH + dd] / dn;
    float s = val;
    #pragma unroll
    for (int o = 1; o <= 32; o <<= 1) s += __shfl_xor(s, o);
    if ((t & 63) == 0) red1[t >> 6] = s;
    __syncthreads();
    const float mean = (red1[0] + red1[1] + red1[2] + red1[3]) * (1.0f / DIM);
    const float d = val - mean;
    float vs = d * d;
    #pragma unroll
    for (int o = 1; o <= 32; o <<= 1) vs += __shfl_xor(vs, o);
    if ((t & 63) == 0) red2[t >> 6] = vs;
    __syncthreads();
    const float var = (red2[0] + red2[1] + red2[2] + red2[3]) * (1.0f / DIM);
    out[(size_t)(b * NKS + k) * DIM + t] = d * rsqrtf(var + 1e-5f) * ga[t] + gb[t];
}

extern "C" void kernel_launch(void* const* d_in, const int* in_sizes, int n_in,
                              void* d_out, int out_size, void* d_ws, size_t ws_size,
                              hipStream_t stream) {
    const float* X      = (const float*)d_in[0];
    const float* mu     = (const float*)d_in[1];
    const float* ln_s_g = (const float*)d_in[2];
    const float* ln_s_b = (const float*)d_in[3];
    const float* Wq     = (const float*)d_in[4];
    const float* bq     = (const float*)d_in[5];
    const float* Wk     = (const float*)d_in[6];
    const float* bk     = (const float*)d_in[7];
    const float* Wv     = (const float*)d_in[8];
    const float* bv     = (const float*)d_in[9];
    const float* ln_a_g = (const float*)d_in[10];
    const float* ln_a_b = (const float*)d_in[11];
    float* out = (float*)d_out;

    char* ws = (char*)d_ws;
    float*          Q   = (float*)(ws);                  //  65536 B
    unsigned short* W2T = (unsigned short*)(ws + 65536); // 262144 B
    float*          b2  = (float*)(ws + 327680);         //   2048 B
    float*          num = (float*)(ws + 329728);         // 262144 B
    float*          den = (float*)(ws + 591872);         //   4096 B

    hipMemsetAsync(ws + 329728, 0, 262144 + 4096, stream);  // zero num+den
    hipLaunchKernelGGL(k_q,     dim3(64),  dim3(256), 0, stream, mu, ln_s_g, ln_s_b, Wq, bq, Q);
    hipLaunchKernelGGL(k_fold,  dim3(512), dim3(256), 0, stream, Q, Wk, bk, Wv, bv, W2T, b2);
    hipLaunchKernelGGL(k_main,  dim3(512), dim3(512), 0, stream, X, W2T, b2, num, den);
    hipLaunchKernelGGL(k_final, dim3(256), dim3(256), 0, stream, num, den, ln_a_g, ln_a_b, out);
}